// Round 1
// baseline (6023.566 us; speedup 1.0000x reference)
//
#include <hip/hip_runtime.h>
#include <cstddef>

// Problem constants
#define NQ 4096   // query rows
#define NS 4096   // source rows
#define CH 512    // channels
#define NH 8      // heads
#define HC 4096   // NH*CH

// ---------------- generic tiled fp32 GEMM + bias: C = A@B + bias ----------------
#define GT 64
#define GKT 16

__global__ __launch_bounds__(256) void gemm_bias_f32(
    const float* __restrict__ A, const float* __restrict__ B,
    const float* __restrict__ bias, float* __restrict__ C,
    int M, int Nc, int K)
{
  __shared__ float As[GKT][GT + 4];
  __shared__ float Bs[GKT][GT + 4];
  const int tid = threadIdx.x;
  const int tx = tid & 15, ty = tid >> 4;
  const int m0 = blockIdx.y * GT, n0 = blockIdx.x * GT;
  const int ar = tid >> 2, ak = (tid & 3) << 2;
  const int bk = tid >> 4, bn = (tid & 15) << 2;

  float acc[4][4];
#pragma unroll
  for (int i = 0; i < 4; ++i)
#pragma unroll
    for (int j = 0; j < 4; ++j) acc[i][j] = 0.f;

  for (int k0 = 0; k0 < K; k0 += GKT) {
    float4 av = *(const float4*)(A + (size_t)(m0 + ar) * K + (k0 + ak));
    float4 bv = *(const float4*)(B + (size_t)(k0 + bk) * Nc + (n0 + bn));
    __syncthreads();   // previous compute done before overwrite
    As[ak + 0][ar] = av.x;
    As[ak + 1][ar] = av.y;
    As[ak + 2][ar] = av.z;
    As[ak + 3][ar] = av.w;
    *(float4*)&Bs[bk][bn] = bv;
    __syncthreads();
#pragma unroll
    for (int kk = 0; kk < GKT; ++kk) {
      float4 a4 = *(const float4*)&As[kk][ty << 2];
      float4 b4 = *(const float4*)&Bs[kk][tx << 2];
      float a[4] = {a4.x, a4.y, a4.z, a4.w};
      float b[4] = {b4.x, b4.y, b4.z, b4.w};
#pragma unroll
      for (int i = 0; i < 4; ++i)
#pragma unroll
        for (int j = 0; j < 4; ++j) acc[i][j] += a[i] * b[j];
    }
  }

#pragma unroll
  for (int i = 0; i < 4; ++i) {
    const int m = m0 + (ty << 2) + i;
#pragma unroll
    for (int j = 0; j < 4; ++j) {
      const int n = n0 + (tx << 2) + j;
      C[(size_t)m * Nc + n] = acc[i][j] + bias[n];
    }
  }
}

// ---------------- fused scores + softmax(over heads) + T accumulation ----------------
// T[n,h,k] = sum_l softmax_h(q[n,h,:]·k[l,h,:] / 8)[h] * value[l,k]
// sl[n,h]  = sum_l w[n,l,h]   (needed for the bias term of the deferred v-projection)
#define NT 16   // query rows per block
#define LT 8    // source rows per phase

__global__ __launch_bounds__(512, 2) void attn_heads_softmax(
    const float* __restrict__ qm, const float* __restrict__ km,
    const float* __restrict__ valm, float* __restrict__ T,
    float* __restrict__ sl)
{
  __shared__ float q_s[NT][CH];       // 32 KB, XOR-swizzled (hh*64-stride reads)
  __shared__ float sw[NT][LT][9];     // scores -> weights (+1 pad vs 8)
  const int tid = threadIdx.x;
  const int n0 = blockIdx.x * NT;

  for (int i = tid; i < NT * CH; i += 512) {
    const int row = i >> 9, col = i & 511;
    q_s[row][col ^ (((col >> 6) & 7) << 2)] = qm[(size_t)(n0 + row) * CH + col];
  }

  float acc[NT][8];
#pragma unroll
  for (int i = 0; i < NT; ++i)
#pragma unroll
    for (int j = 0; j < 8; ++j) acc[i][j] = 0.f;

  float slacc[8];
#pragma unroll
  for (int h = 0; h < 8; ++h) slacc[h] = 0.f;

  const int hsel = tid >> 6;          // head of this thread's output columns
  const int kb = (tid & 63) << 3;     // value column base (8 cols/thread)

  __syncthreads();

  for (int l0 = 0; l0 < NS; l0 += LT) {
    // --- scores: 16n x 8l x 8h = 1024 dots of length 64; 2 per thread ---
    float sc[2];
#pragma unroll
    for (int dd = 0; dd < 2; ++dd) {
      const int d = (tid << 1) + dd;
      const int ni = d >> 6;
      const int lj = (d >> 3) & 7;
      const int hh = d & 7;
      const float* kp = km + (size_t)(l0 + lj) * CH + (hh << 6);
      float s = 0.f;
#pragma unroll
      for (int j = 0; j < 64; j += 4) {
        float4 kv = *(const float4*)(kp + j);
        float4 qv = *(const float4*)&q_s[ni][((hh << 6) + j) ^ (hh << 2)];
        s += qv.x * kv.x + qv.y * kv.y + qv.z * kv.z + qv.w * kv.w;
      }
      sc[dd] = s * 0.125f;   // 1/sqrt(64)
    }
    __syncthreads();         // previous PV done reading sw
#pragma unroll
    for (int dd = 0; dd < 2; ++dd) {
      const int d = (tid << 1) + dd;
      sw[d >> 6][(d >> 3) & 7][d & 7] = sc[dd];
    }
    __syncthreads();
    // --- softmax over the 8 heads, one (ni,lj) per thread ---
    if (tid < NT * LT) {
      const int ni = tid >> 3, lj = tid & 7;
      float mx = sw[ni][lj][0];
#pragma unroll
      for (int h = 1; h < 8; ++h) mx = fmaxf(mx, sw[ni][lj][h]);
      float e[8], ssum = 0.f;
#pragma unroll
      for (int h = 0; h < 8; ++h) { e[h] = __expf(sw[ni][lj][h] - mx); ssum += e[h]; }
      const float inv = 1.f / ssum;
#pragma unroll
      for (int h = 0; h < 8; ++h) {
        const float w = e[h] * inv;
        sw[ni][lj][h] = w;
        slacc[h] += w;
      }
    }
    __syncthreads();
    // --- T accumulation: acc[ni][j] += w[ni][lj][hsel] * value[l][kb+j] ---
#pragma unroll
    for (int lj = 0; lj < LT; ++lj) {
      const float* vp = valm + (size_t)(l0 + lj) * CH + kb;
      const float4 v0 = *(const float4*)vp;
      const float4 v1 = *(const float4*)(vp + 4);
#pragma unroll
      for (int ni = 0; ni < NT; ++ni) {
        const float w = sw[ni][lj][hsel];   // wave-uniform LDS broadcast
        acc[ni][0] += w * v0.x; acc[ni][1] += w * v0.y;
        acc[ni][2] += w * v0.z; acc[ni][3] += w * v0.w;
        acc[ni][4] += w * v1.x; acc[ni][5] += w * v1.y;
        acc[ni][6] += w * v1.z; acc[ni][7] += w * v1.w;
      }
    }
  }

  // --- reduce slacc (held by the 128 softmax threads) into sl[n,h] ---
  __syncthreads();
  if (tid < NT * LT) {
    const int ni = tid >> 3, lj = tid & 7;
#pragma unroll
    for (int h = 0; h < 8; ++h) sw[ni][lj][h] = slacc[h];
  }
  __syncthreads();
  if (tid < NT * LT) {
    const int ni = tid >> 3, h = tid & 7;
    float s = 0.f;
#pragma unroll
    for (int lj = 0; lj < 8; ++lj) s += sw[ni][lj][h];
    sl[(size_t)(n0 + ni) * NH + h] = s;
  }

  // --- write T tile: col = tid*8 == hsel*512 + kb ---
  const int cb = tid << 3;
#pragma unroll
  for (int ni = 0; ni < NT; ++ni) {
    float* tp = T + (size_t)(n0 + ni) * HC + cb;
    *(float4*)tp       = make_float4(acc[ni][0], acc[ni][1], acc[ni][2], acc[ni][3]);
    *(float4*)(tp + 4) = make_float4(acc[ni][4], acc[ni][5], acc[ni][6], acc[ni][7]);
  }
}

// ---------------- out[n, h*512+c] = T[n,h,:] @ Wv[:, h*512+c] + sl[n,h]*bias[...] ----------------
__global__ __launch_bounds__(256) void gemm_headmix_f32(
    const float* __restrict__ T, const float* __restrict__ Wv,
    const float* __restrict__ bias, const float* __restrict__ sl,
    float* __restrict__ C)
{
  __shared__ float As[GKT][GT + 4];
  __shared__ float Bs[GKT][GT + 4];
  const int tid = threadIdx.x;
  const int tx = tid & 15, ty = tid >> 4;
  const int m0 = blockIdx.y * GT, n0 = blockIdx.x * GT;
  const int h = n0 >> 9;              // 64-col tiles never straddle a head (512 % 64 == 0)
  const int ar = tid >> 2, ak = (tid & 3) << 2;
  const int bk = tid >> 4, bn = (tid & 15) << 2;

  float acc[4][4];
#pragma unroll
  for (int i = 0; i < 4; ++i)
#pragma unroll
    for (int j = 0; j < 4; ++j) acc[i][j] = 0.f;

  for (int k0 = 0; k0 < CH; k0 += GKT) {
    float4 av = *(const float4*)(T + (size_t)(m0 + ar) * HC + (h << 9) + (k0 + ak));
    float4 bv = *(const float4*)(Wv + (size_t)(k0 + bk) * HC + (n0 + bn));
    __syncthreads();
    As[ak + 0][ar] = av.x;
    As[ak + 1][ar] = av.y;
    As[ak + 2][ar] = av.z;
    As[ak + 3][ar] = av.w;
    *(float4*)&Bs[bk][bn] = bv;
    __syncthreads();
#pragma unroll
    for (int kk = 0; kk < GKT; ++kk) {
      float4 a4 = *(const float4*)&As[kk][ty << 2];
      float4 b4 = *(const float4*)&Bs[kk][tx << 2];
      float a[4] = {a4.x, a4.y, a4.z, a4.w};
      float b[4] = {b4.x, b4.y, b4.z, b4.w};
#pragma unroll
      for (int i = 0; i < 4; ++i)
#pragma unroll
        for (int j = 0; j < 4; ++j) acc[i][j] += a[i] * b[j];
    }
  }

#pragma unroll
  for (int i = 0; i < 4; ++i) {
    const int m = m0 + (ty << 2) + i;
    const float slv = sl[(size_t)m * NH + h];
#pragma unroll
    for (int j = 0; j < 4; ++j) {
      const int n = n0 + (tx << 2) + j;
      C[(size_t)m * HC + n] = acc[i][j] + slv * bias[n];
    }
  }
}

// ---------------- launcher ----------------
extern "C" void kernel_launch(void* const* d_in, const int* in_sizes, int n_in,
                              void* d_out, int out_size, void* d_ws, size_t ws_size,
                              hipStream_t stream)
{
  const float* query     = (const float*)d_in[0];
  const float* source    = (const float*)d_in[1];
  const float* Wv_out_w  = (const float*)d_in[2];
  const float* Wv_out_b  = (const float*)d_in[3];
  const float* Wq_w      = (const float*)d_in[4];
  const float* Wq_b      = (const float*)d_in[5];
  const float* Wk_w      = (const float*)d_in[6];
  const float* Wk_b      = (const float*)d_in[7];
  const float* Wv_attn_w = (const float*)d_in[8];
  const float* Wv_attn_b = (const float*)d_in[9];
  float* out = (float*)d_out;
  float* ws  = (float*)d_ws;

  // ws layout (floats): q[2M] k[2M] value[2M] T[16M] sl[32K]  => ~92.4 MB
  float* qb   = ws;
  float* kb   = ws + 2097152;
  float* valb = ws + 4194304;
  float* Tb   = ws + 6291456;
  float* slb  = ws + 23068672;

  dim3 gProj(CH / GT, NQ / GT);   // (8, 64)
  gemm_bias_f32<<<gProj, 256, 0, stream>>>(source, Wv_out_w, Wv_out_b, valb, NS, CH, CH);
  gemm_bias_f32<<<gProj, 256, 0, stream>>>(query,  Wq_w,     Wq_b,     qb,   NQ, CH, CH);
  gemm_bias_f32<<<gProj, 256, 0, stream>>>(source, Wk_w,     Wk_b,     kb,   NS, CH, CH);

  attn_heads_softmax<<<NQ / NT, 512, 0, stream>>>(qb, kb, valb, Tb, slb);

  dim3 gMix(HC / GT, NQ / GT);    // (64, 64)
  gemm_headmix_f32<<<gMix, 256, 0, stream>>>(Tb, Wv_attn_w, Wv_attn_b, slb, out);
}

// Round 3
// 716.129 us; speedup vs baseline: 8.4113x; 8.4113x over previous
//
#include <hip/hip_runtime.h>
#include <cstddef>
#include <cstdint>

#define NQ 4096
#define NS 4096
#define CH 512
#define NH 8
#define HC 4096   // NH*CH

typedef unsigned short u16;
typedef __attribute__((ext_vector_type(8))) short short8;
typedef __attribute__((ext_vector_type(4))) float f32x4;

__device__ __forceinline__ u16 f2b(float f) {
  unsigned u = __float_as_uint(f);
  return (u16)((u + 0x7fffu + ((u >> 16) & 1u)) >> 16);
}
__device__ __forceinline__ float b2f(u16 h) {
  return __uint_as_float(((unsigned)h) << 16);
}
__device__ __forceinline__ f32x4 mfma16(short8 a, short8 b, f32x4 c) {
  return __builtin_amdgcn_mfma_f32_16x16x32_bf16(a, b, c, 0, 0, 0);
}
__device__ __forceinline__ void gload_lds16(const void* g, void* l) {
  __builtin_amdgcn_global_load_lds(
      (const __attribute__((address_space(1))) void*)g,
      (__attribute__((address_space(3))) void*)l, 16, 0, 0);
}

// ---------------- converts ----------------
__global__ __launch_bounds__(256) void convert_flat(
    const float* __restrict__ in, u16* __restrict__ out, int n4)
{
  int idx = blockIdx.x * 256 + threadIdx.x;
  int stride = gridDim.x * 256;
  for (int i = idx; i < n4; i += stride) {
    float4 v = ((const float4*)in)[i];
    ushort4 o;
    o.x = f2b(v.x); o.y = f2b(v.y); o.z = f2b(v.z); o.w = f2b(v.w);
    ((ushort4*)out)[i] = o;
  }
}

// in [R][C] f32 -> out [C][R] bf16
__global__ __launch_bounds__(256) void transpose_convert(
    const float* __restrict__ in, u16* __restrict__ out, int R, int C)
{
  __shared__ u16 tile[32][33];
  int tid = threadIdx.x;
  int tx = tid & 31, ty = tid >> 5;  // ty 0..7
#pragma unroll
  for (int i = 0; i < 4; ++i) {
    int r = blockIdx.y * 32 + ty + i * 8;
    int c = blockIdx.x * 32 + tx;
    tile[ty + i * 8][tx] = f2b(in[(size_t)r * C + c]);
  }
  __syncthreads();
#pragma unroll
  for (int i = 0; i < 4; ++i) {
    int co = blockIdx.x * 32 + ty + i * 8;
    int ro = blockIdx.y * 32 + tx;
    out[(size_t)co * R + ro] = tile[tx][ty + i * 8];
  }
}

// ---------------- generic MFMA GEMM core ----------------
// A [M][K] bf16 row-major, Bt [N][K] bf16 row-major (B transposed), K % 32 == 0.
// MODE 0: C bf16 [M][ldc] = A@B + bias[n]                      (projections q,k)
// MODE 1: C bf16 transposed [N][ldc] (ldc = M stride) + bias   (value -> valueT)
// MODE 2: pass2: per-head A plane (blockIdx.z), C bf16 col-offset z*512,
//         rowsum of A tile -> sl[m*8+z]  (BM=32, BN=256)
// MODE 3: headmix: A col-offset z*512, Bt offset z*512*512, C f32 col-offset z*512,
//         C += sl[m*8+z]*bias[n]
template <int MODE>
__global__ __launch_bounds__(256) void gemm_core(
    const u16* __restrict__ A, int lda,
    const u16* __restrict__ Bt, int ldb,
    u16* __restrict__ Cb, float* __restrict__ Cf, int ldc,
    const float* __restrict__ bias, float* __restrict__ sl,
    int K, size_t aPlane)
{
  constexpr int BM = (MODE == 2) ? 32 : 128;
  constexpr int BN = (MODE == 2) ? 256 : 128;
  constexpr int WC = (MODE == 2) ? 4 : 2;
  constexpr int FM = (MODE == 2) ? 2 : 4;   // BM/(waves_r*16)
  constexpr int FN = (MODE == 2) ? 4 : 4;   // BN/(WC*16)
  constexpr int ABYTES = BM * 64;           // BM*32*2
  constexpr int NCH = (BM + BN) * 64 / 1024;

  __shared__ u16 smem[(BM + BN) * 32];
  u16* As = smem;
  u16* Bs = smem + BM * 32;

  const int tid = threadIdx.x;
  const int wid = tid >> 6, lane = tid & 63;
  const int wr = wid / WC, wc = wid % WC;
  const int fr = wr * FM * 16, fc = wc * FN * 16;
  const int m0 = blockIdx.y * BM, n0 = blockIdx.x * BN;
  const int bz = blockIdx.z;

  if constexpr (MODE == 2) { A += (size_t)bz * aPlane; Cb += (size_t)bz * 512; }
  if constexpr (MODE == 3) {
    A += (size_t)bz * 512; Bt += (size_t)bz * 512 * 512;
    bias += (size_t)bz * 512; Cf += (size_t)bz * 512;
  }

  f32x4 acc[FM][FN];
#pragma unroll
  for (int m = 0; m < FM; ++m)
#pragma unroll
    for (int n = 0; n < FN; ++n)
#pragma unroll
      for (int i = 0; i < 4; ++i) acc[m][n][i] = 0.f;

  float rowsum = 0.f;
  const int lcol = (lane & 3) << 3;       // staging col (elems)
  const int lrow4 = lane >> 2;            // staging row within 16-row chunk

  for (int k0 = 0; k0 < K; k0 += 32) {
    for (int c = wid; c < NCH; c += 4) {
      int boff = c << 10;
      const u16* g;
      if (boff < ABYTES) {
        int r = (boff >> 6) + lrow4;
        g = A + (size_t)(m0 + r) * lda + (k0 + lcol);
      } else {
        int r = ((boff - ABYTES) >> 6) + lrow4;
        g = Bt + (size_t)(n0 + r) * ldb + (k0 + lcol);
      }
      gload_lds16(g, (char*)smem + boff);
    }
    __syncthreads();

    if constexpr (MODE == 2) {
      if (blockIdx.x == 0 && tid < BM) {
        float r = 0.f;
#pragma unroll
        for (int j = 0; j < 32; ++j) r += b2f(As[tid * 32 + j]);
        rowsum += r;
      }
    }

    short8 af[FM], bq[FN];
    const int kg = (lane >> 4) << 3;
#pragma unroll
    for (int m = 0; m < FM; ++m)
      af[m] = *(const short8*)(As + (size_t)(fr + m * 16 + (lane & 15)) * 32 + kg);
#pragma unroll
    for (int n = 0; n < FN; ++n)
      bq[n] = *(const short8*)(Bs + (size_t)(fc + n * 16 + (lane & 15)) * 32 + kg);
#pragma unroll
    for (int m = 0; m < FM; ++m)
#pragma unroll
      for (int n = 0; n < FN; ++n)
        acc[m][n] = mfma16(af[m], bq[n], acc[m][n]);
    __syncthreads();
  }

  const int crow = (lane >> 4) << 2;
  const int ccol = lane & 15;

  if constexpr (MODE == 0) {
#pragma unroll
    for (int n = 0; n < FN; ++n) {
      int gn = n0 + fc + n * 16 + ccol;
      float bv = bias[gn];
#pragma unroll
      for (int m = 0; m < FM; ++m)
#pragma unroll
        for (int i = 0; i < 4; ++i) {
          int gm = m0 + fr + m * 16 + crow + i;
          Cb[(size_t)gm * ldc + gn] = f2b(acc[m][n][i] + bv);
        }
    }
  } else if constexpr (MODE == 1) {
#pragma unroll
    for (int n = 0; n < FN; ++n) {
      int gn = n0 + fc + n * 16 + ccol;
      float bv = bias[gn];
#pragma unroll
      for (int m = 0; m < FM; ++m) {
        int mb = m0 + fr + m * 16 + crow;
        ushort4 o;
        o.x = f2b(acc[m][n][0] + bv); o.y = f2b(acc[m][n][1] + bv);
        o.z = f2b(acc[m][n][2] + bv); o.w = f2b(acc[m][n][3] + bv);
        *(ushort4*)(Cb + (size_t)gn * ldc + mb) = o;
      }
    }
  } else if constexpr (MODE == 2) {
#pragma unroll
    for (int m = 0; m < FM; ++m)
#pragma unroll
      for (int i = 0; i < 4; ++i) {
        int gm = m0 + fr + m * 16 + crow + i;
#pragma unroll
        for (int n = 0; n < FN; ++n) {
          int gn = n0 + fc + n * 16 + ccol;
          Cb[(size_t)gm * ldc + gn] = f2b(acc[m][n][i]);
        }
      }
    if (blockIdx.x == 0 && tid < BM) sl[(size_t)(m0 + tid) * 8 + bz] = rowsum;
  } else {  // MODE 3
#pragma unroll
    for (int m = 0; m < FM; ++m)
#pragma unroll
      for (int i = 0; i < 4; ++i) {
        int gm = m0 + fr + m * 16 + crow + i;
        float slv = sl[(size_t)gm * 8 + bz];
#pragma unroll
        for (int n = 0; n < FN; ++n) {
          int gn = n0 + fc + n * 16 + ccol;
          Cf[(size_t)gm * ldc + gn] = acc[m][n][i] + slv * bias[gn];
        }
      }
  }
}

// ---------------- pass 1: scores (MFMA) + per-lane softmax over heads -> W bf16 ----------------
// block: 256 thr = 4 waves, each wave an independent 16n x 32l tile, all 8 heads.
__global__ __launch_bounds__(256) void attn_pass1(
    const u16* __restrict__ q, const u16* __restrict__ kmat,
    u16* __restrict__ W, int nbase, size_t plane)
{
  const int tid = threadIdx.x, wid = tid >> 6, lane = tid & 63;
  const int n0 = nbase + blockIdx.y * 16;
  const int l0 = blockIdx.x * 128 + wid * 32;
  const int r16 = lane & 15, kg = (lane >> 4) << 3;

  f32x4 acc[8][2];
#pragma unroll
  for (int h = 0; h < 8; ++h)
#pragma unroll
    for (int f = 0; f < 2; ++f)
#pragma unroll
      for (int i = 0; i < 4; ++i) acc[h][f][i] = 0.f;

  const u16* qrow = q + (size_t)(n0 + r16) * CH + kg;
  const u16* k0p = kmat + (size_t)(l0 + r16) * CH + kg;
  const u16* k1p = k0p + (size_t)16 * CH;

#pragma unroll
  for (int h = 0; h < 8; ++h) {
#pragma unroll
    for (int kk = 0; kk < 2; ++kk) {
      int off = h * 64 + kk * 32;
      short8 a  = *(const short8*)(qrow + off);
      short8 b0 = *(const short8*)(k0p + off);
      short8 b1 = *(const short8*)(k1p + off);
      acc[h][0] = mfma16(a, b0, acc[h][0]);
      acc[h][1] = mfma16(a, b1, acc[h][1]);
    }
  }

  const int rowl = blockIdx.y * 16 + ((lane >> 4) << 2);  // chunk-local W row base
#pragma unroll
  for (int f = 0; f < 2; ++f) {
#pragma unroll
    for (int i = 0; i < 4; ++i) {
      float s[8], mx = -3e38f;
#pragma unroll
      for (int h = 0; h < 8; ++h) { s[h] = acc[h][f][i] * 0.125f; mx = fmaxf(mx, s[h]); }
      float sum = 0.f;
#pragma unroll
      for (int h = 0; h < 8; ++h) { s[h] = __expf(s[h] - mx); sum += s[h]; }
      float inv = 1.0f / sum;
      size_t base = (size_t)(rowl + i) * NS + l0 + f * 16 + (lane & 15);
#pragma unroll
      for (int h = 0; h < 8; ++h) W[(size_t)h * plane + base] = f2b(s[h] * inv);
    }
  }
}

// ---------------- launcher ----------------
extern "C" void kernel_launch(void* const* d_in, const int* in_sizes, int n_in,
                              void* d_out, int out_size, void* d_ws, size_t ws_size,
                              hipStream_t stream)
{
  const float* query   = (const float*)d_in[0];
  const float* source  = (const float*)d_in[1];
  const float* Wvo_w   = (const float*)d_in[2];
  const float* Wvo_b   = (const float*)d_in[3];
  const float* Wq_w    = (const float*)d_in[4];
  const float* Wq_b    = (const float*)d_in[5];
  const float* Wk_w    = (const float*)d_in[6];
  const float* Wk_b    = (const float*)d_in[7];
  const float* Wva_w   = (const float*)d_in[8];
  const float* Wva_b   = (const float*)d_in[9];
  float* out = (float*)d_out;

  char* base = (char*)d_ws;
  size_t o = 0;
  auto alloc = [&](size_t b) -> char* {
    char* p = base + o;
    o += (b + 255) & ~(size_t)255;
    return p;
  };
  u16* query_bf  = (u16*)alloc((size_t)NQ * CH * 2);
  u16* source_bf = (u16*)alloc((size_t)NS * CH * 2);
  u16* WqT  = (u16*)alloc((size_t)CH * CH * 2);
  u16* WkT  = (u16*)alloc((size_t)CH * CH * 2);
  u16* WvoT = (u16*)alloc((size_t)CH * CH * 2);
  u16* WvaT = (u16*)alloc((size_t)CH * HC * 2);   // [4096][512]
  u16* qb   = (u16*)alloc((size_t)NQ * CH * 2);
  u16* kb   = (u16*)alloc((size_t)NS * CH * 2);
  u16* valT = (u16*)alloc((size_t)CH * NS * 2);   // [512][4096]
  u16* Tb   = (u16*)alloc((size_t)NQ * HC * 2);   // [4096][4096] bf16, col h*512+k
  float* slb = (float*)alloc((size_t)NQ * NH * 4);
  size_t fixed = o;

  int c = 16;
  for (int cand = 1; cand <= 16; cand <<= 1) {
    if (fixed + (size_t)8 * (NQ / cand) * NS * 2 <= ws_size) { c = cand; break; }
  }
  const int rows = NQ / c;
  u16* Wb = (u16*)alloc((size_t)8 * rows * NS * 2);
  const size_t plane = (size_t)rows * NS;

  // converts
  convert_flat<<<1024, 256, 0, stream>>>(query, query_bf, NQ * CH / 4);
  convert_flat<<<1024, 256, 0, stream>>>(source, source_bf, NS * CH / 4);
  transpose_convert<<<dim3(16, 16), 256, 0, stream>>>(Wq_w, WqT, CH, CH);
  transpose_convert<<<dim3(16, 16), 256, 0, stream>>>(Wk_w, WkT, CH, CH);
  transpose_convert<<<dim3(16, 16), 256, 0, stream>>>(Wvo_w, WvoT, CH, CH);
  transpose_convert<<<dim3(128, 16), 256, 0, stream>>>(Wva_w, WvaT, CH, HC);

  // projections (bf16 MFMA)
  gemm_core<0><<<dim3(4, 32), 256, 0, stream>>>(query_bf, CH, WqT, CH, qb, nullptr, CH,
                                                Wq_b, nullptr, CH, 0);
  gemm_core<0><<<dim3(4, 32), 256, 0, stream>>>(source_bf, CH, WkT, CH, kb, nullptr, CH,
                                                Wk_b, nullptr, CH, 0);
  gemm_core<1><<<dim3(4, 32), 256, 0, stream>>>(source_bf, CH, WvoT, CH, valT, nullptr, NS,
                                                Wvo_b, nullptr, CH, 0);

  // chunked: pass1 (scores+softmax -> W), pass2 (T = W_h @ value, + sl rowsums)
  for (int ci = 0; ci < c; ++ci) {
    int nb = ci * rows;
    attn_pass1<<<dim3(32, rows / 16), 256, 0, stream>>>(qb, kb, Wb, nb, plane);
    gemm_core<2><<<dim3(2, rows / 32, 8), 256, 0, stream>>>(
        Wb, NS, valT, NS, Tb + (size_t)nb * HC, nullptr, HC,
        nullptr, slb + (size_t)nb * NH, NS, plane);
  }

  // headmix: out_h = T_h @ Wv_h + sl*b
  gemm_core<3><<<dim3(4, 32, 8), 256, 0, stream>>>(
      Tb, HC, WvaT, CH, nullptr, out, HC, Wva_b, slb, CH, 0);
}

// Round 5
// 677.305 us; speedup vs baseline: 8.8934x; 1.0573x over previous
//
#include <hip/hip_runtime.h>
#include <cstddef>
#include <cstdint>

#define NQ 4096
#define NS 4096
#define CH 512
#define NH 8
#define HC 4096   // NH*CH

typedef unsigned short u16;
typedef __attribute__((ext_vector_type(8))) short short8;
typedef __attribute__((ext_vector_type(4))) float f32x4;

__device__ __forceinline__ u16 f2b(float f) {
  unsigned u = __float_as_uint(f);
  return (u16)((u + 0x7fffu + ((u >> 16) & 1u)) >> 16);
}
__device__ __forceinline__ f32x4 mfma16(short8 a, short8 b, f32x4 c) {
  return __builtin_amdgcn_mfma_f32_16x16x32_bf16(a, b, c, 0, 0, 0);
}
__device__ __forceinline__ void gload_lds16(const void* g, void* l) {
  __builtin_amdgcn_global_load_lds(
      (const __attribute__((address_space(1))) void*)g,
      (__attribute__((address_space(3))) void*)l, 16, 0, 0);
}

// ---------------- converts ----------------
__global__ __launch_bounds__(256) void convert_flat(
    const float* __restrict__ in, u16* __restrict__ out, int n4)
{
  int idx = blockIdx.x * 256 + threadIdx.x;
  int stride = gridDim.x * 256;
  for (int i = idx; i < n4; i += stride) {
    float4 v = ((const float4*)in)[i];
    ushort4 o;
    o.x = f2b(v.x); o.y = f2b(v.y); o.z = f2b(v.z); o.w = f2b(v.w);
    ((ushort4*)out)[i] = o;
  }
}

// in [R][C] f32 -> out [C][R] bf16
__global__ __launch_bounds__(256) void transpose_convert(
    const float* __restrict__ in, u16* __restrict__ out, int R, int C)
{
  __shared__ u16 tile[32][33];
  int tid = threadIdx.x;
  int tx = tid & 31, ty = tid >> 5;
#pragma unroll
  for (int i = 0; i < 4; ++i) {
    int r = blockIdx.y * 32 + ty + i * 8;
    int c = blockIdx.x * 32 + tx;
    tile[ty + i * 8][tx] = f2b(in[(size_t)r * C + c]);
  }
  __syncthreads();
#pragma unroll
  for (int i = 0; i < 4; ++i) {
    int co = blockIdx.x * 32 + ty + i * 8;
    int ro = blockIdx.y * 32 + tx;
    out[(size_t)co * R + ro] = tile[tx][ty + i * 8];
  }
}

// ---------------- 128x128 MFMA GEMM core (m97 structure) ----------------
// A [M][K] bf16 row-major, Bt [N][K] bf16 row-major (B transposed), K % 32 == 0.
// MODE 0: C bf16 [M][ldc] = A@B + bias[n]                      (projections)
// MODE 1: C bf16 transposed: C[gn*ldc + gm] = (A@B + bias)[gm][gn]   (V2T)
// MODE 3: batched over blockIdx.z=h: A += z*aPlane (lda=NS),
//         Bt += z*512*ldb, Cf += z*512; C f32 = A@B (no bias)   (pass2: out)
template <int MODE>
__global__ __launch_bounds__(256) void gemm_core(
    const u16* __restrict__ A, int lda,
    const u16* __restrict__ Bt, int ldb,
    u16* __restrict__ Cb, float* __restrict__ Cf, int ldc,
    const float* __restrict__ bias,
    int K, size_t aPlane)
{
  constexpr int BM = 128, BN = 128;
  constexpr int FM = 4, FN = 4;
  constexpr int ABYTES = BM * 64;
  constexpr int NCH = (BM + BN) * 64 / 1024;   // 16

  __shared__ u16 smem[(BM + BN) * 32];
  u16* As = smem;
  u16* Bs = smem + BM * 32;

  const int tid = threadIdx.x;
  const int wid = tid >> 6, lane = tid & 63;
  const int wr = wid >> 1, wc = wid & 1;
  const int fr = wr * FM * 16, fc = wc * FN * 16;
  const int m0 = blockIdx.y * BM, n0 = blockIdx.x * BN;

  if constexpr (MODE == 3) {
    const int bz = blockIdx.z;
    A += (size_t)bz * aPlane;
    Bt += (size_t)bz * 512 * ldb;
    Cf += (size_t)bz * 512;
  }

  f32x4 acc[FM][FN];
#pragma unroll
  for (int m = 0; m < FM; ++m)
#pragma unroll
    for (int n = 0; n < FN; ++n)
#pragma unroll
      for (int i = 0; i < 4; ++i) acc[m][n][i] = 0.f;

  const int lcol = (lane & 3) << 3;
  const int lrow4 = lane >> 2;

  for (int k0 = 0; k0 < K; k0 += 32) {
    for (int c = wid; c < NCH; c += 4) {
      int boff = c << 10;
      const u16* g;
      if (boff < ABYTES) {
        int r = (boff >> 6) + lrow4;
        g = A + (size_t)(m0 + r) * lda + (k0 + lcol);
      } else {
        int r = ((boff - ABYTES) >> 6) + lrow4;
        g = Bt + (size_t)(n0 + r) * ldb + (k0 + lcol);
      }
      gload_lds16(g, (char*)smem + boff);
    }
    __syncthreads();

    short8 af[FM], bq[FN];
    const int kg = (lane >> 4) << 3;
#pragma unroll
    for (int m = 0; m < FM; ++m)
      af[m] = *(const short8*)(As + (size_t)(fr + m * 16 + (lane & 15)) * 32 + kg);
#pragma unroll
    for (int n = 0; n < FN; ++n)
      bq[n] = *(const short8*)(Bs + (size_t)(fc + n * 16 + (lane & 15)) * 32 + kg);
#pragma unroll
    for (int m = 0; m < FM; ++m)
#pragma unroll
      for (int n = 0; n < FN; ++n)
        acc[m][n] = mfma16(af[m], bq[n], acc[m][n]);
    __syncthreads();
  }

  const int crow = (lane >> 4) << 2;
  const int ccol = lane & 15;

  if constexpr (MODE == 0) {
#pragma unroll
    for (int n = 0; n < FN; ++n) {
      int gn = n0 + fc + n * 16 + ccol;
      float bv = bias[gn];
#pragma unroll
      for (int m = 0; m < FM; ++m)
#pragma unroll
        for (int i = 0; i < 4; ++i) {
          int gm = m0 + fr + m * 16 + crow + i;
          Cb[(size_t)gm * ldc + gn] = f2b(acc[m][n][i] + bv);
        }
    }
  } else if constexpr (MODE == 1) {
#pragma unroll
    for (int n = 0; n < FN; ++n) {
      int gn = n0 + fc + n * 16 + ccol;
      float bv = bias[gn];
#pragma unroll
      for (int m = 0; m < FM; ++m) {
        int mb = m0 + fr + m * 16 + crow;
        ushort4 o;
        o.x = f2b(acc[m][n][0] + bv); o.y = f2b(acc[m][n][1] + bv);
        o.z = f2b(acc[m][n][2] + bv); o.w = f2b(acc[m][n][3] + bv);
        *(ushort4*)(Cb + (size_t)gn * ldc + mb) = o;
      }
    }
  } else {  // MODE 3
#pragma unroll
    for (int m = 0; m < FM; ++m)
#pragma unroll
      for (int i = 0; i < 4; ++i) {
        int gm = m0 + fr + m * 16 + crow + i;
#pragma unroll
        for (int n = 0; n < FN; ++n) {
          int gn = n0 + fc + n * 16 + ccol;
          Cf[(size_t)gm * ldc + gn] = acc[m][n][i];
        }
      }
  }
}

// ---------------- pass 1: S^T via MFMA + per-lane softmax over heads -> W[h][nloc][l] ----------------
// block: 256 thr = 4 waves; block tile 16n x 128l (wave w: l in [l0+w*32, +32)).
// Swapped operands: acc = mfma(k_frag, q_frag) => C row = l (4-consec per reg quad), col = n.
// W rows are CHUNK-LOCAL (q reads use nbase + local row).
__global__ __launch_bounds__(256) void attn_pass1(
    const u16* __restrict__ q, const u16* __restrict__ kmat,
    u16* __restrict__ W, int nbase, size_t plane)
{
  __shared__ u16 lbuf[16384];   // [h][16 n][128 l] bf16, 32 KB, swizzled
  char* lb = (char*)lbuf;

  const int tid = threadIdx.x, wid = tid >> 6, lane = tid & 63;
  const int nloc0 = blockIdx.y * 16;            // chunk-local n base
  const int l0 = blockIdx.x * 128;
  const int lw = l0 + wid * 32;                 // this wave's l base
  const int r16 = lane & 15, g = lane >> 4;
  const int kg = g << 3;

  // hoist q fragments: qf[h*2+kk], global row nbase + nloc0 + r16
  short8 qf[16];
  const u16* qrow = q + (size_t)(nbase + nloc0 + r16) * CH + kg;
#pragma unroll
  for (int h = 0; h < 8; ++h)
#pragma unroll
    for (int kk = 0; kk < 2; ++kk)
      qf[h * 2 + kk] = *(const short8*)(qrow + h * 64 + kk * 32);

  f32x4 acc[8][2];
#pragma unroll
  for (int h = 0; h < 8; ++h)
#pragma unroll
    for (int f = 0; f < 2; ++f)
#pragma unroll
      for (int i = 0; i < 4; ++i) acc[h][f][i] = 0.f;

#pragma unroll
  for (int f = 0; f < 2; ++f) {
    const u16* krow = kmat + (size_t)(lw + f * 16 + r16) * CH + kg;
#pragma unroll
    for (int h = 0; h < 8; ++h)
#pragma unroll
      for (int kk = 0; kk < 2; ++kk) {
        short8 kf = *(const short8*)(krow + h * 64 + kk * 32);
        acc[h][f] = mfma16(kf, qf[h * 2 + kk], acc[h][f]);
      }
  }

  // softmax over heads at each (f,i); C row = l = lw + f*16 + g*4 + i, col = n = nloc0 + r16
  const int nn = r16;
#pragma unroll
  for (int f = 0; f < 2; ++f) {
    u16 wb[4][8];
#pragma unroll
    for (int i = 0; i < 4; ++i) {
      float s[8], mx = -3e38f;
#pragma unroll
      for (int h = 0; h < 8; ++h) { s[h] = acc[h][f][i] * 0.125f; mx = fmaxf(mx, s[h]); }
      float sum = 0.f;
#pragma unroll
      for (int h = 0; h < 8; ++h) { s[h] = __expf(s[h] - mx); sum += s[h]; }
      float inv = 1.0f / sum;
#pragma unroll
      for (int h = 0; h < 8; ++h) wb[i][h] = f2b(s[h] * inv);
    }
    // pack 4 consecutive l per head -> 8B LDS store (swizzled)
    const int lloc = wid * 32 + f * 16 + g * 4;   // block-local l of reg i=0
#pragma unroll
    for (int h = 0; h < 8; ++h) {
      unsigned p0 = (unsigned)wb[0][h] | ((unsigned)wb[1][h] << 16);
      unsigned p1 = (unsigned)wb[2][h] | ((unsigned)wb[3][h] << 16);
      int wa = (h << 12) + (nn << 8) + (lloc << 1);
      wa ^= (nn & 7) << 4;
      *(uint2*)(lb + wa) = make_uint2(p0, p1);
    }
  }
  __syncthreads();

  // coalesced writeout: per h, thread t -> nloc = nloc0 + (t>>4), 8 l-values at (t&15)*8
  const int rn = tid >> 4, rl = (tid & 15) << 3;
#pragma unroll
  for (int h = 0; h < 8; ++h) {
    int ra = (h << 12) + (rn << 8) + (rl << 1);
    ra ^= (rn & 7) << 4;
    uint4 v = *(const uint4*)(lb + ra);
    *(uint4*)(W + (size_t)h * plane + (size_t)(nloc0 + rn) * NS + l0 + rl) = v;
  }
}

// ---------------- launcher ----------------
extern "C" void kernel_launch(void* const* d_in, const int* in_sizes, int n_in,
                              void* d_out, int out_size, void* d_ws, size_t ws_size,
                              hipStream_t stream)
{
  const float* query   = (const float*)d_in[0];
  const float* source  = (const float*)d_in[1];
  const float* Wvo_w   = (const float*)d_in[2];
  const float* Wvo_b   = (const float*)d_in[3];
  const float* Wq_w    = (const float*)d_in[4];
  const float* Wq_b    = (const float*)d_in[5];
  const float* Wk_w    = (const float*)d_in[6];
  const float* Wk_b    = (const float*)d_in[7];
  const float* Wva_w   = (const float*)d_in[8];
  const float* Wva_b   = (const float*)d_in[9];
  float* out = (float*)d_out;

  char* base = (char*)d_ws;
  size_t o = 0;
  auto alloc = [&](size_t b) -> char* {
    char* p = base + o;
    o += (b + 255) & ~(size_t)255;
    return p;
  };
  u16* query_bf  = (u16*)alloc((size_t)NQ * CH * 2);
  u16* source_bf = (u16*)alloc((size_t)NS * CH * 2);
  u16* WqT  = (u16*)alloc((size_t)CH * CH * 2);
  u16* WkT  = (u16*)alloc((size_t)CH * CH * 2);
  u16* WvoT = (u16*)alloc((size_t)CH * CH * 2);
  u16* WvaT = (u16*)alloc((size_t)CH * HC * 2);   // [4096 hc][512 k]
  u16* qb   = (u16*)alloc((size_t)NQ * CH * 2);
  u16* kb   = (u16*)alloc((size_t)NS * CH * 2);
  u16* valr = (u16*)alloc((size_t)NS * CH * 2);   // value row-major [4096][512]
  u16* V2T  = (u16*)alloc((size_t)HC * NS * 2);   // [4096 hc][4096 l]
  size_t fixed = o;

  // adaptive chunking of W over query rows (ws_size is ~<326 MB: full W won't fit)
  int c = 32;
  for (int cand = 1; cand <= 32; cand <<= 1) {
    if (fixed + (size_t)NH * (NQ / cand) * NS * 2 <= ws_size) { c = cand; break; }
  }
  const int rows = NQ / c;
  u16* Wb = (u16*)alloc((size_t)NH * rows * NS * 2);  // W[h][rows][l], chunk-local rows
  const size_t plane = (size_t)rows * NS;

  // converts
  convert_flat<<<1024, 256, 0, stream>>>(query, query_bf, NQ * CH / 4);
  convert_flat<<<1024, 256, 0, stream>>>(source, source_bf, NS * CH / 4);
  transpose_convert<<<dim3(16, 16), 256, 0, stream>>>(Wq_w, WqT, CH, CH);
  transpose_convert<<<dim3(16, 16), 256, 0, stream>>>(Wk_w, WkT, CH, CH);
  transpose_convert<<<dim3(16, 16), 256, 0, stream>>>(Wvo_w, WvoT, CH, CH);
  transpose_convert<<<dim3(128, 16), 256, 0, stream>>>(Wva_w, WvaT, CH, HC);

  // projections: qb = query@Wq+b, kb = source@Wk+b, valr = source@Wvo+b
  gemm_core<0><<<dim3(4, 32), 256, 0, stream>>>(query_bf, CH, WqT, CH, qb, nullptr, CH,
                                                Wq_b, CH, 0);
  gemm_core<0><<<dim3(4, 32), 256, 0, stream>>>(source_bf, CH, WkT, CH, kb, nullptr, CH,
                                                Wk_b, CH, 0);
  gemm_core<0><<<dim3(4, 32), 256, 0, stream>>>(source_bf, CH, WvoT, CH, valr, nullptr, CH,
                                                Wvo_b, CH, 0);

  // V2T[hc][l] = (valr @ Wva + b)^T  (bias folded => no sl correction anywhere)
  gemm_core<1><<<dim3(32, 32), 256, 0, stream>>>(valr, CH, WvaT, CH, V2T, nullptr, NS,
                                                 Wva_b, CH, 0);

  // chunked: pass1 (W chunk), pass2 (out rows chunk)
  for (int ci = 0; ci < c; ++ci) {
    const int nb = ci * rows;
    attn_pass1<<<dim3(32, rows / 16), 256, 0, stream>>>(qb, kb, Wb, nb, plane);
    gemm_core<3><<<dim3(4, rows / 128, 8), 256, 0, stream>>>(
        Wb, NS, V2T, NS, nullptr, out + (size_t)nb * HC, HC, nullptr, NS, plane);
  }
}

// Round 6
// 659.503 us; speedup vs baseline: 9.1335x; 1.0270x over previous
//
#include <hip/hip_runtime.h>
#include <cstddef>
#include <cstdint>

#define NQ 4096
#define NS 4096
#define CH 512
#define NH 8
#define HC 4096   // NH*CH

typedef unsigned short u16;
typedef __attribute__((ext_vector_type(8))) short short8;
typedef __attribute__((ext_vector_type(4))) float f32x4;

__device__ __forceinline__ u16 f2b(float f) {
  unsigned u = __float_as_uint(f);
  return (u16)((u + 0x7fffu + ((u >> 16) & 1u)) >> 16);
}
__device__ __forceinline__ f32x4 mfma16(short8 a, short8 b, f32x4 c) {
  return __builtin_amdgcn_mfma_f32_16x16x32_bf16(a, b, c, 0, 0, 0);
}
__device__ __forceinline__ void gload_lds16(const void* g, void* l) {
  __builtin_amdgcn_global_load_lds(
      (const __attribute__((address_space(1))) void*)g,
      (__attribute__((address_space(3))) void*)l, 16, 0, 0);
}

// ---------------- converts ----------------
__global__ __launch_bounds__(256) void convert_flat(
    const float* __restrict__ in, u16* __restrict__ out, int n4)
{
  int idx = blockIdx.x * 256 + threadIdx.x;
  int stride = gridDim.x * 256;
  for (int i = idx; i < n4; i += stride) {
    float4 v = ((const float4*)in)[i];
    ushort4 o;
    o.x = f2b(v.x); o.y = f2b(v.y); o.z = f2b(v.z); o.w = f2b(v.w);
    ((ushort4*)out)[i] = o;
  }
}

// in [R][C] f32 -> out [C][R] bf16
__global__ __launch_bounds__(256) void transpose_convert(
    const float* __restrict__ in, u16* __restrict__ out, int R, int C)
{
  __shared__ u16 tile[32][33];
  int tid = threadIdx.x;
  int tx = tid & 31, ty = tid >> 5;
#pragma unroll
  for (int i = 0; i < 4; ++i) {
    int r = blockIdx.y * 32 + ty + i * 8;
    int c = blockIdx.x * 32 + tx;
    tile[ty + i * 8][tx] = f2b(in[(size_t)r * C + c]);
  }
  __syncthreads();
#pragma unroll
  for (int i = 0; i < 4; ++i) {
    int co = blockIdx.x * 32 + ty + i * 8;
    int ro = blockIdx.y * 32 + tx;
    out[(size_t)co * R + ro] = tile[tx][ty + i * 8];
  }
}

// bcomb[hc] = sum_c Wvo_b[c] * Wva_w[c][hc] + Wva_b[hc]
__global__ __launch_bounds__(256) void make_bcomb(
    const float* __restrict__ Wva_w, const float* __restrict__ Wvo_b,
    const float* __restrict__ Wva_b, float* __restrict__ bcomb)
{
  int hc = blockIdx.x * 256 + threadIdx.x;
  float s = Wva_b[hc];
  for (int c = 0; c < CH; ++c) s += Wvo_b[c] * Wva_w[(size_t)c * HC + hc];
  bcomb[hc] = s;
}

// ---------------- 128x128 MFMA GEMM core (m97 structure) ----------------
// A [M][K] bf16 row-major, Bt [N][K] bf16 row-major (B transposed), K % 32 == 0.
// MODE 0: C bf16 = A@B + bias[col]      (projections q,k)       2-D grid
// MODE 2: C bf16 = A@B + bias[row]      (V2T from WcombT)       2-D grid
// MODE 5: C bf16 = A@B                  (WcombT)                2-D grid
// MODE 3: C f32 (+)= A@B, batched: 1-D grid bid -> z=bid&7 (head -> XCD),
//         loc=bid>>3, x=loc&3 (col-tile, fastest), y=loc>>2 (row-tile);
//         A += z*aPlane, Bt += z*512*ldb, Cf += z*512; accum flag RMW.
template <int MODE>
__global__ __launch_bounds__(256) void gemm_core(
    const u16* __restrict__ A, int lda,
    const u16* __restrict__ Bt, int ldb,
    u16* __restrict__ Cb, float* __restrict__ Cf, int ldc,
    const float* __restrict__ bias,
    int K, size_t aPlane, int accum)
{
  constexpr int BM = 128, BN = 128;
  constexpr int FM = 4, FN = 4;
  constexpr int ABYTES = BM * 64;
  constexpr int NCH = (BM + BN) * 64 / 1024;   // 16

  __shared__ u16 smem[(BM + BN) * 32];
  u16* As = smem;
  u16* Bs = smem + BM * 32;

  const int tid = threadIdx.x;
  const int wid = tid >> 6, lane = tid & 63;
  const int wr = wid >> 1, wc = wid & 1;
  const int fr = wr * FM * 16, fc = wc * FN * 16;

  int m0, n0;
  if constexpr (MODE == 3) {
    const int bid = blockIdx.x;
    const int z = bid & 7, loc = bid >> 3;
    m0 = (loc >> 2) * BM;
    n0 = (loc & 3) * BN;
    A += (size_t)z * aPlane;
    Bt += (size_t)z * 512 * ldb;
    Cf += (size_t)z * 512;
  } else {
    m0 = blockIdx.y * BM;
    n0 = blockIdx.x * BN;
  }

  f32x4 acc[FM][FN];
#pragma unroll
  for (int m = 0; m < FM; ++m)
#pragma unroll
    for (int n = 0; n < FN; ++n)
#pragma unroll
      for (int i = 0; i < 4; ++i) acc[m][n][i] = 0.f;

  const int lcol = (lane & 3) << 3;
  const int lrow4 = lane >> 2;

  for (int k0 = 0; k0 < K; k0 += 32) {
    for (int c = wid; c < NCH; c += 4) {
      int boff = c << 10;
      const u16* g;
      if (boff < ABYTES) {
        int r = (boff >> 6) + lrow4;
        g = A + (size_t)(m0 + r) * lda + (k0 + lcol);
      } else {
        int r = ((boff - ABYTES) >> 6) + lrow4;
        g = Bt + (size_t)(n0 + r) * ldb + (k0 + lcol);
      }
      gload_lds16(g, (char*)smem + boff);
    }
    __syncthreads();

    short8 af[FM], bq[FN];
    const int kg = (lane >> 4) << 3;
#pragma unroll
    for (int m = 0; m < FM; ++m)
      af[m] = *(const short8*)(As + (size_t)(fr + m * 16 + (lane & 15)) * 32 + kg);
#pragma unroll
    for (int n = 0; n < FN; ++n)
      bq[n] = *(const short8*)(Bs + (size_t)(fc + n * 16 + (lane & 15)) * 32 + kg);
#pragma unroll
    for (int m = 0; m < FM; ++m)
#pragma unroll
      for (int n = 0; n < FN; ++n)
        acc[m][n] = mfma16(af[m], bq[n], acc[m][n]);
    __syncthreads();
  }

  const int crow = (lane >> 4) << 2;
  const int ccol = lane & 15;

  if constexpr (MODE == 0) {
#pragma unroll
    for (int n = 0; n < FN; ++n) {
      int gn = n0 + fc + n * 16 + ccol;
      float bv = bias[gn];
#pragma unroll
      for (int m = 0; m < FM; ++m)
#pragma unroll
        for (int i = 0; i < 4; ++i) {
          int gm = m0 + fr + m * 16 + crow + i;
          Cb[(size_t)gm * ldc + gn] = f2b(acc[m][n][i] + bv);
        }
    }
  } else if constexpr (MODE == 2) {
#pragma unroll
    for (int m = 0; m < FM; ++m)
#pragma unroll
      for (int i = 0; i < 4; ++i) {
        int gm = m0 + fr + m * 16 + crow + i;
        float bv = bias[gm];
#pragma unroll
        for (int n = 0; n < FN; ++n) {
          int gn = n0 + fc + n * 16 + ccol;
          Cb[(size_t)gm * ldc + gn] = f2b(acc[m][n][i] + bv);
        }
      }
  } else if constexpr (MODE == 5) {
#pragma unroll
    for (int m = 0; m < FM; ++m)
#pragma unroll
      for (int i = 0; i < 4; ++i) {
        int gm = m0 + fr + m * 16 + crow + i;
#pragma unroll
        for (int n = 0; n < FN; ++n) {
          int gn = n0 + fc + n * 16 + ccol;
          Cb[(size_t)gm * ldc + gn] = f2b(acc[m][n][i]);
        }
      }
  } else {  // MODE 3
#pragma unroll
    for (int m = 0; m < FM; ++m)
#pragma unroll
      for (int i = 0; i < 4; ++i) {
        int gm = m0 + fr + m * 16 + crow + i;
#pragma unroll
        for (int n = 0; n < FN; ++n) {
          int gn = n0 + fc + n * 16 + ccol;
          size_t idx = (size_t)gm * ldc + gn;
          float v = acc[m][n][i];
          if (accum) v += Cf[idx];
          Cf[idx] = v;
        }
      }
  }
}

// ---------------- pass 1: S^T via MFMA + per-lane softmax over heads -> W[h][n][l_loc] ----------------
// l-chunked: this dispatch covers source rows [lbase, lbase+LCH). W rows are full-n,
// W row stride = LCH. Block tile 16n x 128l; wave w handles l in [l0+w*32, +32).
// Swapped operands: acc = mfma(k_frag, q_frag) => C row = l (4-consec per reg quad), col = n.
__global__ __launch_bounds__(256) void attn_pass1(
    const u16* __restrict__ q, const u16* __restrict__ kmat,
    u16* __restrict__ W, int lbase, int LCH, size_t plane)
{
  __shared__ u16 lbuf[16384];   // [h][16 n][128 l] bf16, 32 KB, swizzled
  char* lb = (char*)lbuf;

  const int tid = threadIdx.x, wid = tid >> 6, lane = tid & 63;
  const int n0 = blockIdx.y * 16;               // global n base
  const int l0 = blockIdx.x * 128;              // chunk-local l base
  const int lw = lbase + l0 + wid * 32;         // global l base for this wave
  const int r16 = lane & 15, g = lane >> 4;
  const int kg = g << 3;

  // hoist q fragments: qf[h*2+kk], row n0+r16
  short8 qf[16];
  const u16* qrow = q + (size_t)(n0 + r16) * CH + kg;
#pragma unroll
  for (int h = 0; h < 8; ++h)
#pragma unroll
    for (int kk = 0; kk < 2; ++kk)
      qf[h * 2 + kk] = *(const short8*)(qrow + h * 64 + kk * 32);

  f32x4 acc[8][2];
#pragma unroll
  for (int h = 0; h < 8; ++h)
#pragma unroll
    for (int f = 0; f < 2; ++f)
#pragma unroll
      for (int i = 0; i < 4; ++i) acc[h][f][i] = 0.f;

#pragma unroll
  for (int f = 0; f < 2; ++f) {
    const u16* krow = kmat + (size_t)(lw + f * 16 + r16) * CH + kg;
#pragma unroll
    for (int h = 0; h < 8; ++h)
#pragma unroll
      for (int kk = 0; kk < 2; ++kk) {
        short8 kf = *(const short8*)(krow + h * 64 + kk * 32);
        acc[h][f] = mfma16(kf, qf[h * 2 + kk], acc[h][f]);
      }
  }

  // softmax over heads at each (f,i); C row = l, col = n = n0 + r16
  const int nn = r16;
#pragma unroll
  for (int f = 0; f < 2; ++f) {
    u16 wb[4][8];
#pragma unroll
    for (int i = 0; i < 4; ++i) {
      float s[8], mx = -3e38f;
#pragma unroll
      for (int h = 0; h < 8; ++h) { s[h] = acc[h][f][i] * 0.125f; mx = fmaxf(mx, s[h]); }
      float sum = 0.f;
#pragma unroll
      for (int h = 0; h < 8; ++h) { s[h] = __expf(s[h] - mx); sum += s[h]; }
      float inv = 1.0f / sum;
#pragma unroll
      for (int h = 0; h < 8; ++h) wb[i][h] = f2b(s[h] * inv);
    }
    // pack 4 consecutive l per head -> 8B LDS store (swizzled)
    const int lloc = wid * 32 + f * 16 + g * 4;   // block-local l of reg i=0
#pragma unroll
    for (int h = 0; h < 8; ++h) {
      unsigned p0 = (unsigned)wb[0][h] | ((unsigned)wb[1][h] << 16);
      unsigned p1 = (unsigned)wb[2][h] | ((unsigned)wb[3][h] << 16);
      int wa = (h << 12) + (nn << 8) + (lloc << 1);
      wa ^= (nn & 7) << 4;
      *(uint2*)(lb + wa) = make_uint2(p0, p1);
    }
  }
  __syncthreads();

  // coalesced writeout: per h, thread t -> n = n0 + (t>>4), 8 l-values at (t&15)*8
  const int rn = tid >> 4, rl = (tid & 15) << 3;
#pragma unroll
  for (int h = 0; h < 8; ++h) {
    int ra = (h << 12) + (rn << 8) + (rl << 1);
    ra ^= (rn & 7) << 4;
    uint4 v = *(const uint4*)(lb + ra);
    *(uint4*)(W + (size_t)h * plane + (size_t)(n0 + rn) * LCH + l0 + rl) = v;
  }
}

// ---------------- launcher ----------------
extern "C" void kernel_launch(void* const* d_in, const int* in_sizes, int n_in,
                              void* d_out, int out_size, void* d_ws, size_t ws_size,
                              hipStream_t stream)
{
  const float* query   = (const float*)d_in[0];
  const float* source  = (const float*)d_in[1];
  const float* Wvo_w   = (const float*)d_in[2];
  const float* Wvo_b   = (const float*)d_in[3];
  const float* Wq_w    = (const float*)d_in[4];
  const float* Wq_b    = (const float*)d_in[5];
  const float* Wk_w    = (const float*)d_in[6];
  const float* Wk_b    = (const float*)d_in[7];
  const float* Wva_w   = (const float*)d_in[8];
  const float* Wva_b   = (const float*)d_in[9];
  float* out = (float*)d_out;

  char* base = (char*)d_ws;
  size_t o = 0;
  auto alloc = [&](size_t b) -> char* {
    char* p = base + o;
    o += (b + 255) & ~(size_t)255;
    return p;
  };
  u16* query_bf  = (u16*)alloc((size_t)NQ * CH * 2);
  u16* source_bf = (u16*)alloc((size_t)NS * CH * 2);
  u16* WqT     = (u16*)alloc((size_t)CH * CH * 2);
  u16* WkT     = (u16*)alloc((size_t)CH * CH * 2);
  u16* WvaT    = (u16*)alloc((size_t)CH * HC * 2);   // [4096 hc][512 c]
  u16* Wvo_bf  = (u16*)alloc((size_t)CH * CH * 2);   // [512 cs][512 c] row-major
  u16* WcombT  = (u16*)alloc((size_t)HC * CH * 2);   // [4096 hc][512 cs]
  float* bcomb = (float*)alloc((size_t)HC * 4);
  u16* qb   = (u16*)alloc((size_t)NQ * CH * 2);
  u16* kb   = (u16*)alloc((size_t)NS * CH * 2);
  u16* V2T  = (u16*)alloc((size_t)HC * NS * 2);      // [4096 hc][4096 l]
  size_t fixed = o;

  // l-chunking of W (full W = 268 MB won't fit alongside fixed ~58 MB)
  int c = 32;
  for (int cand = 1; cand <= 32; cand <<= 1) {
    if (fixed + (size_t)NH * NQ * (NS / cand) * 2 <= ws_size) { c = cand; break; }
  }
  const int LCH = NS / c;
  u16* Wb = (u16*)alloc((size_t)NH * NQ * LCH * 2);  // W[h][n][l_loc]
  const size_t plane = (size_t)NQ * LCH;

  // converts
  convert_flat<<<1024, 256, 0, stream>>>(query, query_bf, NQ * CH / 4);
  convert_flat<<<1024, 256, 0, stream>>>(source, source_bf, NS * CH / 4);
  convert_flat<<<256, 256, 0, stream>>>(Wvo_w, Wvo_bf, CH * CH / 4);
  transpose_convert<<<dim3(16, 16), 256, 0, stream>>>(Wq_w, WqT, CH, CH);
  transpose_convert<<<dim3(16, 16), 256, 0, stream>>>(Wk_w, WkT, CH, CH);
  transpose_convert<<<dim3(128, 16), 256, 0, stream>>>(Wva_w, WvaT, CH, HC);
  make_bcomb<<<16, 256, 0, stream>>>(Wva_w, Wvo_b, Wva_b, bcomb);

  // WcombT[hc][cs] = sum_c WvaT[hc][c] * Wvo[cs][c]   (no bias)
  gemm_core<5><<<dim3(4, 32), 256, 0, stream>>>(WvaT, CH, Wvo_bf, CH, WcombT, nullptr, CH,
                                                nullptr, CH, 0, 0);

  // projections: qb = query@Wq+b, kb = source@Wk+b
  gemm_core<0><<<dim3(4, 32), 256, 0, stream>>>(query_bf, CH, WqT, CH, qb, nullptr, CH,
                                                Wq_b, CH, 0, 0);
  gemm_core<0><<<dim3(4, 32), 256, 0, stream>>>(source_bf, CH, WkT, CH, kb, nullptr, CH,
                                                Wk_b, CH, 0, 0);

  // V2T[hc][l] = sum_cs WcombT[hc][cs] * source[l][cs] + bcomb[hc]  (row bias)
  gemm_core<2><<<dim3(32, 32), 256, 0, stream>>>(WcombT, CH, source_bf, CH, V2T, nullptr, NS,
                                                 bcomb, CH, 0, 0);

  // chunked over l: pass1 (W chunk), pass2 (out += W_h @ V2T[:, l-chunk])
  for (int ci = 0; ci < c; ++ci) {
    const int lbase = ci * LCH;
    attn_pass1<<<dim3(LCH / 128, NQ / 16), 256, 0, stream>>>(qb, kb, Wb, lbase, LCH, plane);
    gemm_core<3><<<1024, 256, 0, stream>>>(Wb, LCH, V2T + lbase, NS, nullptr, out, HC,
                                           nullptr, LCH, plane, ci > 0 ? 1 : 0);
  }
}

// Round 9
// 654.288 us; speedup vs baseline: 9.2063x; 1.0080x over previous
//
#include <hip/hip_runtime.h>
#include <cstddef>
#include <cstdint>

#define NQ 4096
#define NS 4096
#define CH 512
#define NH 8
#define HC 4096   // NH*CH

typedef unsigned short u16;
typedef __attribute__((ext_vector_type(8))) short short8;
typedef __attribute__((ext_vector_type(4))) float f32x4;

__device__ __forceinline__ u16 f2b(float f) {
  unsigned u = __float_as_uint(f);
  return (u16)((u + 0x7fffu + ((u >> 16) & 1u)) >> 16);
}
__device__ __forceinline__ f32x4 mfma16(short8 a, short8 b, f32x4 c) {
  return __builtin_amdgcn_mfma_f32_16x16x32_bf16(a, b, c, 0, 0, 0);
}
__device__ __forceinline__ void gload_lds16(const void* g, void* l) {
  __builtin_amdgcn_global_load_lds(
      (const __attribute__((address_space(1))) void*)g,
      (__attribute__((address_space(3))) void*)l, 16, 0, 0);
}

// ---------------- converts ----------------
__global__ __launch_bounds__(256) void convert_flat(
    const float* __restrict__ in, u16* __restrict__ out, int n4)
{
  int idx = blockIdx.x * 256 + threadIdx.x;
  int stride = gridDim.x * 256;
  for (int i = idx; i < n4; i += stride) {
    float4 v = ((const float4*)in)[i];
    ushort4 o;
    o.x = f2b(v.x); o.y = f2b(v.y); o.z = f2b(v.z); o.w = f2b(v.w);
    ((ushort4*)out)[i] = o;
  }
}

// in [R][C] f32 -> out [C][R] bf16
__global__ __launch_bounds__(256) void transpose_convert(
    const float* __restrict__ in, u16* __restrict__ out, int R, int C)
{
  __shared__ u16 tile[32][33];
  int tid = threadIdx.x;
  int tx = tid & 31, ty = tid >> 5;
#pragma unroll
  for (int i = 0; i < 4; ++i) {
    int r = blockIdx.y * 32 + ty + i * 8;
    int c = blockIdx.x * 32 + tx;
    tile[ty + i * 8][tx] = f2b(in[(size_t)r * C + c]);
  }
  __syncthreads();
#pragma unroll
  for (int i = 0; i < 4; ++i) {
    int co = blockIdx.x * 32 + ty + i * 8;
    int ro = blockIdx.y * 32 + tx;
    out[(size_t)co * R + ro] = tile[tx][ty + i * 8];
  }
}

// bcomb[hc] = sum_c Wvo_b[c] * Wva_w[c][hc] + Wva_b[hc]
__global__ __launch_bounds__(256) void make_bcomb(
    const float* __restrict__ Wva_w, const float* __restrict__ Wvo_b,
    const float* __restrict__ Wva_b, float* __restrict__ bcomb)
{
  int hc = blockIdx.x * 256 + threadIdx.x;
  float s = Wva_b[hc];
  for (int c = 0; c < CH; ++c) s += Wvo_b[c] * Wva_w[(size_t)c * HC + hc];
  bcomb[hc] = s;
}

// ---------------- 128x128 MFMA GEMM core (single-buffer, 2-barrier) ----------------
// A [M][K] bf16 row-major, Bt [N][K] bf16 row-major (B transposed), K % 32 == 0.
// MODE 0: C bf16 = A@B + bias[col]      (projections q,k)
// MODE 2: C bf16 = A@B + bias[row]      (V2T from WcombT)
// MODE 5: C bf16 = A@B                  (WcombT)
template <int MODE>
__global__ __launch_bounds__(256) void gemm_core(
    const u16* __restrict__ A, int lda,
    const u16* __restrict__ Bt, int ldb,
    u16* __restrict__ Cb, int ldc,
    const float* __restrict__ bias,
    int K)
{
  constexpr int BM = 128, BN = 128;
  constexpr int FM = 4, FN = 4;
  constexpr int ABYTES = BM * 64;
  constexpr int NCH = (BM + BN) * 64 / 1024;   // 16

  __shared__ u16 smem[(BM + BN) * 32];
  u16* As = smem;
  u16* Bs = smem + BM * 32;

  const int tid = threadIdx.x;
  const int wid = tid >> 6, lane = tid & 63;
  const int wr = wid >> 1, wc = wid & 1;
  const int fr = wr * FM * 16, fc = wc * FN * 16;
  const int m0 = blockIdx.y * BM, n0 = blockIdx.x * BN;

  f32x4 acc[FM][FN];
#pragma unroll
  for (int m = 0; m < FM; ++m)
#pragma unroll
    for (int n = 0; n < FN; ++n)
#pragma unroll
      for (int i = 0; i < 4; ++i) acc[m][n][i] = 0.f;

  const int lcol = (lane & 3) << 3;
  const int lrow4 = lane >> 2;

  for (int k0 = 0; k0 < K; k0 += 32) {
    for (int c = wid; c < NCH; c += 4) {
      int boff = c << 10;
      const u16* g;
      if (boff < ABYTES) {
        int r = (boff >> 6) + lrow4;
        g = A + (size_t)(m0 + r) * lda + (k0 + lcol);
      } else {
        int r = ((boff - ABYTES) >> 6) + lrow4;
        g = Bt + (size_t)(n0 + r) * ldb + (k0 + lcol);
      }
      gload_lds16(g, (char*)smem + boff);
    }
    __syncthreads();

    short8 af[FM], bq[FN];
    const int kg = (lane >> 4) << 3;
#pragma unroll
    for (int m = 0; m < FM; ++m)
      af[m] = *(const short8*)(As + (size_t)(fr + m * 16 + (lane & 15)) * 32 + kg);
#pragma unroll
    for (int n = 0; n < FN; ++n)
      bq[n] = *(const short8*)(Bs + (size_t)(fc + n * 16 + (lane & 15)) * 32 + kg);
#pragma unroll
    for (int m = 0; m < FM; ++m)
#pragma unroll
      for (int n = 0; n < FN; ++n)
        acc[m][n] = mfma16(af[m], bq[n], acc[m][n]);
    __syncthreads();
  }

  const int crow = (lane >> 4) << 2;
  const int ccol = lane & 15;

  if constexpr (MODE == 0) {
#pragma unroll
    for (int n = 0; n < FN; ++n) {
      int gn = n0 + fc + n * 16 + ccol;
      float bv = bias[gn];
#pragma unroll
      for (int m = 0; m < FM; ++m)
#pragma unroll
        for (int i = 0; i < 4; ++i) {
          int gm = m0 + fr + m * 16 + crow + i;
          Cb[(size_t)gm * ldc + gn] = f2b(acc[m][n][i] + bv);
        }
    }
  } else if constexpr (MODE == 2) {
#pragma unroll
    for (int m = 0; m < FM; ++m)
#pragma unroll
      for (int i = 0; i < 4; ++i) {
        int gm = m0 + fr + m * 16 + crow + i;
        float bv = bias[gm];
#pragma unroll
        for (int n = 0; n < FN; ++n) {
          int gn = n0 + fc + n * 16 + ccol;
          Cb[(size_t)gm * ldc + gn] = f2b(acc[m][n][i] + bv);
        }
      }
  } else {  // MODE 5
#pragma unroll
    for (int m = 0; m < FM; ++m)
#pragma unroll
      for (int i = 0; i < 4; ++i) {
        int gm = m0 + fr + m * 16 + crow + i;
#pragma unroll
        for (int n = 0; n < FN; ++n) {
          int gn = n0 + fc + n * 16 + ccol;
          Cb[(size_t)gm * ldc + gn] = f2b(acc[m][n][i]);
        }
      }
  }
}

// ---------------- pass 2: out(+)= W_h @ V2T_h, double-buffered prefetch pipeline ----------------
// 1-D grid: bid -> z=bid&7 (head -> XCD), loc=bid>>3, x=loc&3 (col tile, fastest), y=loc>>2.
// Per iter: stage tile t+1 into buf^1 (4 gload_lds/wave), s_waitcnt vmcnt(4) for tile t,
// barrier, ds_read+16 MFMA on buf, barrier. Load latency spans a full iteration.
__global__ __launch_bounds__(256) void gemm_pass2(
    const u16* __restrict__ A, int lda,        // W[h][4096][LCH]
    const u16* __restrict__ Bt, int ldb,       // V2T (+lbase), rows hc, ldb=NS
    float* __restrict__ Cf, int ldc,           // out, ldc=HC
    int K, size_t aPlane, int accum)
{
  constexpr int BM = 128, BN = 128, BK = 32;
  constexpr int ABYTES = BM * 64;              // A bytes per tile (128 rows x 64 B)

  __shared__ u16 smem[2][(BM + BN) * BK];      // 2 x 16 KB

  const int tid = threadIdx.x;
  const int wid = tid >> 6, lane = tid & 63;
  const int wr = wid >> 1, wc = wid & 1;
  const int fr = wr * 64, fc = wc * 64;

  const int bid = blockIdx.x;
  const int z = bid & 7, loc = bid >> 3;
  const int m0 = (loc >> 2) * BM;
  const int n0 = (loc & 3) * BN;
  A += (size_t)z * aPlane;
  Bt += (size_t)z * 512 * ldb;
  Cf += (size_t)z * 512;

  f32x4 acc[4][4];
#pragma unroll
  for (int m = 0; m < 4; ++m)
#pragma unroll
    for (int n = 0; n < 4; ++n)
#pragma unroll
      for (int i = 0; i < 4; ++i) acc[m][n][i] = 0.f;

  const int lcol = (lane & 3) << 3;
  const int lrow4 = lane >> 2;
  const int kg = (lane >> 4) << 3;

  auto stage = [&](int buf, int k0) {
#pragma unroll
    for (int c = 0; c < 4; ++c) {
      int boff = (c * 4 + wid) << 10;
      const u16* g;
      if (boff < ABYTES) {
        int r = (boff >> 6) + lrow4;
        g = A + (size_t)(m0 + r) * lda + (k0 + lcol);
      } else {
        int r = ((boff - ABYTES) >> 6) + lrow4;
        g = Bt + (size_t)(n0 + r) * ldb + (k0 + lcol);
      }
      gload_lds16(g, (char*)smem[buf] + boff);
    }
  };

  const int nt = K / BK;
  stage(0, 0);

  for (int t = 0; t < nt; ++t) {
    const int cur = t & 1;
    if (t + 1 < nt) {
      stage(cur ^ 1, (t + 1) * BK);
      asm volatile("s_waitcnt vmcnt(4)" ::: "memory");
    } else {
      asm volatile("s_waitcnt vmcnt(0)" ::: "memory");
    }
    __builtin_amdgcn_s_barrier();
    __builtin_amdgcn_sched_barrier(0);

    const u16* As = smem[cur];
    const u16* Bs = smem[cur] + BM * 32;
    short8 af[4], bq[4];
#pragma unroll
    for (int m = 0; m < 4; ++m)
      af[m] = *(const short8*)(As + (size_t)(fr + m * 16 + (lane & 15)) * 32 + kg);
#pragma unroll
    for (int n = 0; n < 4; ++n)
      bq[n] = *(const short8*)(Bs + (size_t)(fc + n * 16 + (lane & 15)) * 32 + kg);
#pragma unroll
    for (int m = 0; m < 4; ++m)
#pragma unroll
      for (int n = 0; n < 4; ++n)
        acc[m][n] = mfma16(af[m], bq[n], acc[m][n]);

    __builtin_amdgcn_sched_barrier(0);
    __builtin_amdgcn_s_barrier();   // all waves done reading buf[cur]; next iter may overwrite
  }

  const int crow = (lane >> 4) << 2;
  const int ccol = lane & 15;
#pragma unroll
  for (int m = 0; m < 4; ++m)
#pragma unroll
    for (int i = 0; i < 4; ++i) {
      int gm = m0 + fr + m * 16 + crow + i;
#pragma unroll
      for (int n = 0; n < 4; ++n) {
        int gn = n0 + fc + n * 16 + ccol;
        size_t idx = (size_t)gm * ldc + gn;
        float v = acc[m][n][i];
        if (accum) v += Cf[idx];
        Cf[idx] = v;
      }
    }
}

// ---------------- pass 1: S^T via MFMA + per-lane softmax over heads -> W[h][n][l_loc] ----------------
// l-chunked: covers source rows [lbase, lbase+LCH). W row stride = LCH.
// Swapped operands: acc = mfma(k_frag, q_frag) => C row = l (4-consec per reg quad), col = n.
__global__ __launch_bounds__(256) void attn_pass1(
    const u16* __restrict__ q, const u16* __restrict__ kmat,
    u16* __restrict__ W, int lbase, int LCH, size_t plane)
{
  __shared__ u16 lbuf[16384];   // [h][16 n][128 l] bf16, 32 KB, swizzled
  char* lb = (char*)lbuf;

  const int tid = threadIdx.x, wid = tid >> 6, lane = tid & 63;
  const int n0 = blockIdx.y * 16;               // global n base
  const int l0 = blockIdx.x * 128;              // chunk-local l base
  const int lw = lbase + l0 + wid * 32;         // global l base for this wave
  const int r16 = lane & 15, g = lane >> 4;
  const int kg = g << 3;

  short8 qf[16];
  const u16* qrow = q + (size_t)(n0 + r16) * CH + kg;
#pragma unroll
  for (int h = 0; h < 8; ++h)
#pragma unroll
    for (int kk = 0; kk < 2; ++kk)
      qf[h * 2 + kk] = *(const short8*)(qrow + h * 64 + kk * 32);

  f32x4 acc[8][2];
#pragma unroll
  for (int h = 0; h < 8; ++h)
#pragma unroll
    for (int f = 0; f < 2; ++f)
#pragma unroll
      for (int i = 0; i < 4; ++i) acc[h][f][i] = 0.f;

#pragma unroll
  for (int f = 0; f < 2; ++f) {
    const u16* krow = kmat + (size_t)(lw + f * 16 + r16) * CH + kg;
#pragma unroll
    for (int h = 0; h < 8; ++h)
#pragma unroll
      for (int kk = 0; kk < 2; ++kk) {
        short8 kf = *(const short8*)(krow + h * 64 + kk * 32);
        acc[h][f] = mfma16(kf, qf[h * 2 + kk], acc[h][f]);
      }
  }

  const int nn = r16;
#pragma unroll
  for (int f = 0; f < 2; ++f) {
    u16 wb[4][8];
#pragma unroll
    for (int i = 0; i < 4; ++i) {
      float s[8], mx = -3e38f;
#pragma unroll
      for (int h = 0; h < 8; ++h) { s[h] = acc[h][f][i] * 0.125f; mx = fmaxf(mx, s[h]); }
      float sum = 0.f;
#pragma unroll
      for (int h = 0; h < 8; ++h) { s[h] = __expf(s[h] - mx); sum += s[h]; }
      float inv = 1.0f / sum;
#pragma unroll
      for (int h = 0; h < 8; ++h) wb[i][h] = f2b(s[h] * inv);
    }
    const int lloc = wid * 32 + f * 16 + g * 4;
#pragma unroll
    for (int h = 0; h < 8; ++h) {
      unsigned p0 = (unsigned)wb[0][h] | ((unsigned)wb[1][h] << 16);
      unsigned p1 = (unsigned)wb[2][h] | ((unsigned)wb[3][h] << 16);
      int wa = (h << 12) + (nn << 8) + (lloc << 1);
      wa ^= (nn & 7) << 4;
      *(uint2*)(lb + wa) = make_uint2(p0, p1);
    }
  }
  __syncthreads();

  const int rn = tid >> 4, rl = (tid & 15) << 3;
#pragma unroll
  for (int h = 0; h < 8; ++h) {
    int ra = (h << 12) + (rn << 8) + (rl << 1);
    ra ^= (rn & 7) << 4;
    uint4 v = *(const uint4*)(lb + ra);
    *(uint4*)(W + (size_t)h * plane + (size_t)(n0 + rn) * LCH + l0 + rl) = v;
  }
}

// ---------------- launcher ----------------
extern "C" void kernel_launch(void* const* d_in, const int* in_sizes, int n_in,
                              void* d_out, int out_size, void* d_ws, size_t ws_size,
                              hipStream_t stream)
{
  const float* query   = (const float*)d_in[0];
  const float* source  = (const float*)d_in[1];
  const float* Wvo_w   = (const float*)d_in[2];
  const float* Wvo_b   = (const float*)d_in[3];
  const float* Wq_w    = (const float*)d_in[4];
  const float* Wq_b    = (const float*)d_in[5];
  const float* Wk_w    = (const float*)d_in[6];
  const float* Wk_b    = (const float*)d_in[7];
  const float* Wva_w   = (const float*)d_in[8];
  const float* Wva_b   = (const float*)d_in[9];
  float* out = (float*)d_out;

  char* base = (char*)d_ws;
  size_t o = 0;
  auto alloc = [&](size_t b) -> char* {
    char* p = base + o;
    o += (b + 255) & ~(size_t)255;
    return p;
  };
  u16* query_bf  = (u16*)alloc((size_t)NQ * CH * 2);
  u16* source_bf = (u16*)alloc((size_t)NS * CH * 2);
  u16* WqT     = (u16*)alloc((size_t)CH * CH * 2);
  u16* WkT     = (u16*)alloc((size_t)CH * CH * 2);
  u16* WvaT    = (u16*)alloc((size_t)CH * HC * 2);   // [4096 hc][512 c]
  u16* Wvo_bf  = (u16*)alloc((size_t)CH * CH * 2);   // [512 cs][512 c] row-major
  u16* WcombT  = (u16*)alloc((size_t)HC * CH * 2);   // [4096 hc][512 cs]
  float* bcomb = (float*)alloc((size_t)HC * 4);
  u16* qb   = (u16*)alloc((size_t)NQ * CH * 2);
  u16* kb   = (u16*)alloc((size_t)NS * CH * 2);
  u16* V2T  = (u16*)alloc((size_t)HC * NS * 2);      // [4096 hc][4096 l]
  size_t fixed = o;

  // l-chunking of W; prefer c=4 (67 MB chunk) so W + V2T + out stay L3-resident
  int c = 32;
  for (int cand = 4; cand <= 32; cand <<= 1) {
    if (fixed + (size_t)NH * NQ * (NS / cand) * 2 <= ws_size) { c = cand; break; }
  }
  const int LCH = NS / c;
  u16* Wb = (u16*)alloc((size_t)NH * NQ * LCH * 2);  // W[h][n][l_loc]
  const size_t plane = (size_t)NQ * LCH;

  // converts
  convert_flat<<<1024, 256, 0, stream>>>(query, query_bf, NQ * CH / 4);
  convert_flat<<<1024, 256, 0, stream>>>(source, source_bf, NS * CH / 4);
  convert_flat<<<256, 256, 0, stream>>>(Wvo_w, Wvo_bf, CH * CH / 4);
  transpose_convert<<<dim3(16, 16), 256, 0, stream>>>(Wq_w, WqT, CH, CH);
  transpose_convert<<<dim3(16, 16), 256, 0, stream>>>(Wk_w, WkT, CH, CH);
  transpose_convert<<<dim3(128, 16), 256, 0, stream>>>(Wva_w, WvaT, CH, HC);
  make_bcomb<<<16, 256, 0, stream>>>(Wva_w, Wvo_b, Wva_b, bcomb);

  // WcombT[hc][cs] = sum_c WvaT[hc][c] * Wvo[cs][c]
  gemm_core<5><<<dim3(4, 32), 256, 0, stream>>>(WvaT, CH, Wvo_bf, CH, WcombT, CH,
                                                nullptr, CH);

  // projections: qb = query@Wq+b, kb = source@Wk+b
  gemm_core<0><<<dim3(4, 32), 256, 0, stream>>>(query_bf, CH, WqT, CH, qb, CH,
                                                Wq_b, CH);
  gemm_core<0><<<dim3(4, 32), 256, 0, stream>>>(source_bf, CH, WkT, CH, kb, CH,
                                                Wk_b, CH);

  // V2T[hc][l] = sum_cs WcombT[hc][cs] * source[l][cs] + bcomb[hc]
  gemm_core<2><<<dim3(32, 32), 256, 0, stream>>>(WcombT, CH, source_bf, CH, V2T, NS,
                                                 bcomb, CH);

  // chunked over l: pass1 (W chunk), pass2 (out += W_h @ V2T[:, l-chunk])
  for (int ci = 0; ci < c; ++ci) {
    const int lbase = ci * LCH;
    attn_pass1<<<dim3(LCH / 128, NQ / 16), 256, 0, stream>>>(qb, kb, Wb, lbase, LCH, plane);
    gemm_pass2<<<1024, 256, 0, stream>>>(Wb, LCH, V2T + lbase, NS, out, HC,
                                         LCH, plane, ci > 0 ? 1 : 0);
  }
}